// Round 1
// baseline (4999.619 us; speedup 1.0000x reference)
//
#include <hip/hip_runtime.h>
#include <hip/hip_bf16.h>
#include <math.h>

// GPT3-like block: QKV proj -> per-head attention (no 1/sqrt(E) scale) ->
// output proj -> FFA -> FFB.  B=1, M=2048, H=16, E=128, D=2048, C=8192.
// Round 0: correct fp32 baseline. 128x128x8 tiled SGEMM, 8x8 per thread.
// All kernels on `stream`; scratch laid out in d_ws with S/FFA aliasing.

#define TBM 128
#define TBN 128
#define TBK 8

// C[M,N] = A[M,K] * B, where B is [K,N] row-major (BT=false) or [N,K]
// row-major (BT=true, i.e. we compute A * B^T over the storage).
// Batched over blockIdx.z with element strides abatch/bbatch/cbatch.
template<bool BT>
__global__ __launch_bounds__(256)
void sgemm(const float* __restrict__ A, const float* __restrict__ B,
           float* __restrict__ C, int M, int N, int K,
           int lda, int ldb, int ldc,
           long long abatch, long long bbatch, long long cbatch)
{
    __shared__ float As[TBK][TBM];
    __shared__ float Bs[TBK][TBN];

    const int z = blockIdx.z;
    A += (long long)z * abatch;
    B += (long long)z * bbatch;
    C += (long long)z * cbatch;

    const int bm = blockIdx.y * TBM;
    const int bn = blockIdx.x * TBN;
    const int t  = threadIdx.x;          // 0..255
    const int tm = (t >> 4) * 8;         // 0..120 row offset in tile
    const int tn = (t & 15) * 8;         // 0..120 col offset in tile

    // A-tile (and NT B-tile) load coords: 128 rows x 8 k, one float4/thread
    const int am = t >> 1;               // 0..127
    const int ak = (t & 1) * 4;          // 0 or 4
    // NN B-tile load coords: 8 k-rows x 128 n, one float4/thread
    const int bkr = t >> 5;              // 0..7
    const int bnc = (t & 31) * 4;        // 0..124

    float acc[8][8] = {};

    for (int k0 = 0; k0 < K; k0 += TBK) {
        float4 a4 = *(const float4*)(A + (long long)(bm + am) * lda + (k0 + ak));
        float4 b4;
        if (BT) {
            b4 = *(const float4*)(B + (long long)(bn + am) * ldb + (k0 + ak));
        } else {
            b4 = *(const float4*)(B + (long long)(k0 + bkr) * ldb + (bn + bnc));
        }
        __syncthreads();   // previous iter's reads done before overwrite
        As[ak + 0][am] = a4.x;
        As[ak + 1][am] = a4.y;
        As[ak + 2][am] = a4.z;
        As[ak + 3][am] = a4.w;
        if (BT) {
            Bs[ak + 0][am] = b4.x;
            Bs[ak + 1][am] = b4.y;
            Bs[ak + 2][am] = b4.z;
            Bs[ak + 3][am] = b4.w;
        } else {
            *(float4*)&Bs[bkr][bnc] = b4;
        }
        __syncthreads();

        #pragma unroll
        for (int kk = 0; kk < TBK; ++kk) {
            float4 a0 = *(const float4*)&As[kk][tm];
            float4 a1 = *(const float4*)&As[kk][tm + 4];
            float4 b0 = *(const float4*)&Bs[kk][tn];
            float4 b1 = *(const float4*)&Bs[kk][tn + 4];
            float a[8] = {a0.x, a0.y, a0.z, a0.w, a1.x, a1.y, a1.z, a1.w};
            float b[8] = {b0.x, b0.y, b0.z, b0.w, b1.x, b1.y, b1.z, b1.w};
            #pragma unroll
            for (int i = 0; i < 8; ++i)
                #pragma unroll
                for (int j = 0; j < 8; ++j)
                    acc[i][j] = fmaf(a[i], b[j], acc[i][j]);
        }
    }

    #pragma unroll
    for (int i = 0; i < 8; ++i) {
        float4 c0 = {acc[i][0], acc[i][1], acc[i][2], acc[i][3]};
        float4 c1 = {acc[i][4], acc[i][5], acc[i][6], acc[i][7]};
        float* crow = C + (long long)(bm + tm + i) * ldc + (bn + tn);
        *(float4*)(crow)     = c0;
        *(float4*)(crow + 4) = c1;
    }
}

// Row softmax over n=2048 elements; grid=(rows, batch); 256 threads/row.
__global__ __launch_bounds__(256)
void softmax_rows(float* __restrict__ S, int n, long long zstride)
{
    float* row = S + (long long)blockIdx.y * zstride + (long long)blockIdx.x * n;
    const int t = threadIdx.x;

    float x[8];
    float m = -INFINITY;
    #pragma unroll
    for (int i = 0; i < 8; ++i) {
        x[i] = row[t + 256 * i];
        m = fmaxf(m, x[i]);
    }
    #pragma unroll
    for (int off = 32; off > 0; off >>= 1)
        m = fmaxf(m, __shfl_xor(m, off, 64));

    __shared__ float redm[4];
    __shared__ float reds[4];
    const int wid = t >> 6;
    if ((t & 63) == 0) redm[wid] = m;
    __syncthreads();
    m = fmaxf(fmaxf(redm[0], redm[1]), fmaxf(redm[2], redm[3]));

    float s = 0.f;
    #pragma unroll
    for (int i = 0; i < 8; ++i) {
        x[i] = __expf(x[i] - m);
        s += x[i];
    }
    #pragma unroll
    for (int off = 32; off > 0; off >>= 1)
        s += __shfl_xor(s, off, 64);
    if ((t & 63) == 0) reds[wid] = s;
    __syncthreads();
    s = reds[0] + reds[1] + reds[2] + reds[3];

    const float inv = 1.0f / s;
    #pragma unroll
    for (int i = 0; i < 8; ++i)
        row[t + 256 * i] = x[i] * inv;
}

extern "C" void kernel_launch(void* const* d_in, const int* in_sizes, int n_in,
                              void* d_out, int out_size, void* d_ws, size_t ws_size,
                              hipStream_t stream)
{
    const float* I    = (const float*)d_in[0];   // [M, D]
    const float* WV   = (const float*)d_in[1];   // [H, E, D] -> [D, D] (he, d)
    const float* WK   = (const float*)d_in[2];
    const float* WQ   = (const float*)d_in[3];
    const float* WZ   = (const float*)d_in[4];   // [H, F, G] -> [D, D] (hf, g)
    const float* WFFA = (const float*)d_in[5];   // [D, C]
    const float* WFFB = (const float*)d_in[6];   // [C, D]
    float* out = (float*)d_out;                  // [M, D] fp32

    const int M = 2048, D = 2048, H = 16, E = 128, C = 8192;
    const long long CH = (long long)M * D;       // elements per M*D buffer

    float* ws  = (float*)d_ws;
    float* Qb  = ws + 0 * CH;
    float* Kb  = ws + 1 * CH;
    float* Vb  = ws + 2 * CH;
    float* AVb = ws + 3 * CH;
    float* Zb  = ws + 4 * CH;
    float* Xb  = ws + 5 * CH;   // scores S (chunked), later FFA (aliased)

    // chunk heads so S fits in Xb; chunk=16 needs 352MB total, chunk=4 needs 151MB
    const size_t need16 = (size_t)(5 * CH + (long long)16 * M * M) * 4;
    const int chunk = (ws_size >= need16) ? 16 : 4;

    const dim3 blk(256);

    // QKV projections: [M,D] x [D,D]^T (weights stored [he][d])
    sgemm<true><<<dim3(16, 16, 1), blk, 0, stream>>>(I, WV, Vb, M, D, D, D, D, D, 0, 0, 0);
    sgemm<true><<<dim3(16, 16, 1), blk, 0, stream>>>(I, WK, Kb, M, D, D, D, D, D, 0, 0, 0);
    sgemm<true><<<dim3(16, 16, 1), blk, 0, stream>>>(I, WQ, Qb, M, D, D, D, D, D, 0, 0, 0);

    // Attention, heads in chunks sharing the S region
    for (int c = 0; c < H; c += chunk) {
        // S[z][m][p] = sum_e Q[m][hE+e] * K[p][hE+e]
        sgemm<true><<<dim3(16, 16, chunk), blk, 0, stream>>>(
            Qb + (long long)c * E, Kb + (long long)c * E, Xb,
            M, M, E, D, D, M, E, E, (long long)M * M);
        softmax_rows<<<dim3(M, chunk), blk, 0, stream>>>(Xb, M, (long long)M * M);
        // AV[m][hE+e] = sum_p P[m][p] * V[p][hE+e]
        sgemm<false><<<dim3(1, 16, chunk), blk, 0, stream>>>(
            Xb, Vb + (long long)c * E, AVb + (long long)c * E,
            M, E, M, M, D, D, (long long)M * M, E, E);
    }

    // Z = AV x WZ   ([M,2048] x [2048,2048])
    sgemm<false><<<dim3(16, 16, 1), blk, 0, stream>>>(AVb, WZ, Zb, M, D, D, D, D, D, 0, 0, 0);
    // FFA = Z x WFFA ([M,2048] x [2048,8192]) -> Xb (aliases dead S)
    sgemm<false><<<dim3(64, 16, 1), blk, 0, stream>>>(Zb, WFFA, Xb, M, C, D, D, C, C, 0, 0, 0);
    // FFB = FFA x WFFB ([M,8192] x [8192,2048]) -> out
    sgemm<false><<<dim3(16, 16, 1), blk, 0, stream>>>(Xb, WFFB, out, M, D, C, C, D, D, 0, 0, 0);
}

// Round 3
// 1269.785 us; speedup vs baseline: 3.9374x; 3.9374x over previous
//
#include <hip/hip_runtime.h>
#include <hip/hip_bf16.h>
#include <math.h>

// GPT3 block on MI355X, round 3: bf16 MFMA GEMMs (m97 structure), tight
// 144 MiB workspace plan (round 2 overflowed: 280 MiB > guaranteed ws).
//   [0,32MiB)   : bI|bWQ|bWK|bWV  -> later S (fp32, 2 heads) -> later bFFA
//   [32,144MiB) : bQ bK bVT bAV bZ bWZT (8 MiB each) + bWFFAT(32) + bWFFBT(32)
// If ws >= 272 MiB, S gets a dedicated 128 MiB region (8-head chunks).

typedef __bf16 bf16_t;
typedef __bf16 bf16x8 __attribute__((ext_vector_type(8)));
typedef float  f32x4  __attribute__((ext_vector_type(4)));

#define AS1 __attribute__((address_space(1)))
#define AS3 __attribute__((address_space(3)))

__device__ __forceinline__ void load16_lds(const bf16_t* g, bf16_t* l) {
    // 16B per lane, LDS dest = wave-uniform base + lane*16
    __builtin_amdgcn_global_load_lds((AS1 void*)g, (AS3 void*)l, 16, 0, 0);
}

// C = A * B^T over storage: A [M,K] lda, B [N,K] ldb.
// CT=false: C [M,N] ldc.  CT=true: writes C^T [N,M] with ld=ldc (TOUT=bf16).
// Batched over blockIdx.z. 256 threads = 4 waves, each wave does 64x64.
template<typename TOUT, bool CT>
__global__ __launch_bounds__(256)
void gemm_bt(const bf16_t* __restrict__ A, const bf16_t* __restrict__ B,
             TOUT* __restrict__ Cc, int Mdim, int Ndim, int Kdim,
             int lda, int ldb, int ldc,
             long long ab, long long bb, long long cb)
{
    __shared__ bf16_t As[128 * 32];
    __shared__ bf16_t Bs[128 * 32];

    const int z = blockIdx.z;
    A  += (long long)z * ab;
    B  += (long long)z * bb;
    Cc += (long long)z * cb;

    const int bm = blockIdx.y * 128;
    const int bn = blockIdx.x * 128;
    const int t  = threadIdx.x;
    const int lane = t & 63;
    const int w    = t >> 6;

    const int wm = (w & 1) * 64;   // wave's 64x64 sub-tile
    const int wn = (w >> 1) * 64;

    // staging: each wave fills 2x 1KB slabs (16 rows x 64B) of As and Bs
    const int sub = lane >> 2;     // row within 16
    const int seg = lane & 3;      // 16B segment within 64B row

    const bf16_t* Ag0 = A + (long long)(bm + w * 32 + sub) * lda + seg * 8;
    const bf16_t* Ag1 = Ag0 + 16LL * lda;
    const bf16_t* Bg0 = B + (long long)(bn + w * 32 + sub) * ldb + seg * 8;
    const bf16_t* Bg1 = Bg0 + 16LL * ldb;

    bf16_t* Al0 = &As[(w * 2 + 0) * 512];
    bf16_t* Al1 = &As[(w * 2 + 1) * 512];
    bf16_t* Bl0 = &Bs[(w * 2 + 0) * 512];
    bf16_t* Bl1 = &Bs[(w * 2 + 1) * 512];

    const int col  = lane & 15;          // MFMA 16-index
    const int koff = (lane >> 4) * 8;    // which 8-chunk of K=32

    f32x4 acc[4][4] = {};

    for (int k0 = 0; k0 < Kdim; k0 += 32) {
        load16_lds(Ag0 + k0, Al0);
        load16_lds(Ag1 + k0, Al1);
        load16_lds(Bg0 + k0, Bl0);
        load16_lds(Bg1 + k0, Bl1);
        __syncthreads();

        bf16x8 af[4], bfr[4];
        #pragma unroll
        for (int mi = 0; mi < 4; ++mi)
            af[mi] = *(const bf16x8*)&As[(wm + mi * 16 + col) * 32 + koff];
        #pragma unroll
        for (int nj = 0; nj < 4; ++nj)
            bfr[nj] = *(const bf16x8*)&Bs[(wn + nj * 16 + col) * 32 + koff];
        #pragma unroll
        for (int mi = 0; mi < 4; ++mi)
            #pragma unroll
            for (int nj = 0; nj < 4; ++nj)
                acc[mi][nj] = __builtin_amdgcn_mfma_f32_16x16x32_bf16(
                    af[mi], bfr[nj], acc[mi][nj], 0, 0, 0);
        __syncthreads();
    }

    // C/D layout (verified m89/m91): col = lane&15, row = (lane>>4)*4 + reg
    const int rbase = (lane >> 4) * 4;
    if constexpr (CT) {
        // write C^T[n][m]; 4 consecutive m per lane -> one 8B store
        #pragma unroll
        for (int mi = 0; mi < 4; ++mi) {
            const long long mb = bm + wm + mi * 16 + rbase;
            #pragma unroll
            for (int nj = 0; nj < 4; ++nj) {
                const long long n = bn + wn + nj * 16 + col;
                union { bf16_t b[4]; unsigned long long u; } o;
                #pragma unroll
                for (int r = 0; r < 4; ++r) o.b[r] = (bf16_t)acc[mi][nj][r];
                *(unsigned long long*)((bf16_t*)Cc + n * ldc + mb) = o.u;
            }
        }
    } else {
        #pragma unroll
        for (int mi = 0; mi < 4; ++mi) {
            #pragma unroll
            for (int r = 0; r < 4; ++r) {
                long long m = bm + wm + mi * 16 + rbase + r;
                TOUT* crow = Cc + m * ldc + bn + wn + col;
                #pragma unroll
                for (int nj = 0; nj < 4; ++nj)
                    crow[nj * 16] = (TOUT)acc[mi][nj][r];
            }
        }
    }
}

// fp32 -> bf16 cast, 4 elems/thread
__global__ __launch_bounds__(256)
void cast_bf16(const float* __restrict__ in, bf16_t* __restrict__ out, long long n)
{
    long long i = ((long long)blockIdx.x * 256 + threadIdx.x) * 4;
    if (i + 3 >= n + 3) return;
    float4 v = *(const float4*)(in + i);
    union { bf16_t b[4]; unsigned long long u; } o;
    o.b[0] = (bf16_t)v.x; o.b[1] = (bf16_t)v.y;
    o.b[2] = (bf16_t)v.z; o.b[3] = (bf16_t)v.w;
    *(unsigned long long*)(out + i) = o.u;
}

// out[c][r] = (bf16) in[r][c];  in is [rows, cols] fp32
__global__ __launch_bounds__(256)
void transpose_to_bf16(const float* __restrict__ in, bf16_t* __restrict__ out,
                       int rows, int cols)
{
    __shared__ bf16_t tile[32][33];
    const int r0 = blockIdx.y * 32, c0 = blockIdx.x * 32;
    const int tx = threadIdx.x & 31, ty = threadIdx.x >> 5;   // ty 0..7
    #pragma unroll
    for (int i = 0; i < 4; ++i) {
        int r = ty + i * 8;
        tile[r][tx] = (bf16_t)in[(long long)(r0 + r) * cols + c0 + tx];
    }
    __syncthreads();
    #pragma unroll
    for (int i = 0; i < 4; ++i) {
        int r = ty + i * 8;
        out[(long long)(c0 + r) * rows + r0 + tx] = tile[tx][r];
    }
}

// softmax over fp32 row of n=2048; writes bf16 P in place (row byte-aliased)
__global__ __launch_bounds__(256)
void softmax_rows_bf16(float* __restrict__ S, int n, long long zstride)
{
    float* row = S + (long long)blockIdx.y * zstride + (long long)blockIdx.x * n;
    bf16_t* prow = (bf16_t*)row;
    const int t = threadIdx.x;

    float x[8];
    float m = -INFINITY;
    #pragma unroll
    for (int i = 0; i < 8; ++i) {
        x[i] = row[t + 256 * i];
        m = fmaxf(m, x[i]);
    }
    #pragma unroll
    for (int off = 32; off > 0; off >>= 1)
        m = fmaxf(m, __shfl_xor(m, off, 64));

    __shared__ float redm[4];
    __shared__ float reds[4];
    const int wid = t >> 6;
    if ((t & 63) == 0) redm[wid] = m;
    __syncthreads();                       // also orders: all row reads done
    m = fmaxf(fmaxf(redm[0], redm[1]), fmaxf(redm[2], redm[3]));

    float s = 0.f;
    #pragma unroll
    for (int i = 0; i < 8; ++i) {
        x[i] = __expf(x[i] - m);
        s += x[i];
    }
    #pragma unroll
    for (int off = 32; off > 0; off >>= 1)
        s += __shfl_xor(s, off, 64);
    if ((t & 63) == 0) reds[wid] = s;
    __syncthreads();                       // writes below happen after this
    s = reds[0] + reds[1] + reds[2] + reds[3];

    const float inv = 1.0f / s;
    #pragma unroll
    for (int i = 0; i < 8; ++i)
        prow[t + 256 * i] = (bf16_t)(x[i] * inv);
}

extern "C" void kernel_launch(void* const* d_in, const int* in_sizes, int n_in,
                              void* d_out, int out_size, void* d_ws, size_t ws_size,
                              hipStream_t stream)
{
    const float* I    = (const float*)d_in[0];   // [M, D]
    const float* WV   = (const float*)d_in[1];   // [H*E, D] = [N,K] (NT-ready)
    const float* WK   = (const float*)d_in[2];
    const float* WQ   = (const float*)d_in[3];
    const float* WZ   = (const float*)d_in[4];   // [hf, g] -> transpose
    const float* WFFA = (const float*)d_in[5];   // [D, C]  -> transpose
    const float* WFFB = (const float*)d_in[6];   // [C, D]  -> transpose
    float* out = (float*)d_out;                  // [M, D] fp32

    const int M = 2048, D = 2048, E = 128, C = 8192;
    const long long MD = (long long)M * D;       // 4M elems
    const size_t MiB = 1024 * 1024;

    char* base = (char*)d_ws;
    // [0,32MiB): bI|bWQ|bWK|bWV, aliased later by S2 (2-head fp32) / bFFA
    bf16_t* bI     = (bf16_t*)(base + 0 * MiB);
    bf16_t* bWQ    = (bf16_t*)(base + 8 * MiB);
    bf16_t* bWK    = (bf16_t*)(base + 16 * MiB);
    bf16_t* bWV    = (bf16_t*)(base + 24 * MiB);
    bf16_t* bQ     = (bf16_t*)(base + 32 * MiB);
    bf16_t* bK     = (bf16_t*)(base + 40 * MiB);
    bf16_t* bVT    = (bf16_t*)(base + 48 * MiB);   // [D, M]
    bf16_t* bAV    = (bf16_t*)(base + 56 * MiB);
    bf16_t* bZ     = (bf16_t*)(base + 64 * MiB);
    bf16_t* bWZT   = (bf16_t*)(base + 72 * MiB);
    bf16_t* bWFFAT = (bf16_t*)(base + 80 * MiB);   // [C, D]
    bf16_t* bWFFBT = (bf16_t*)(base + 112 * MiB);  // [D, C]
    bf16_t* bFFA   = (bf16_t*)(base + 0 * MiB);    // [M, C], after S dead
    // total fixed: 144 MiB (guaranteed: round-0 chunk-4 path used 144 MiB)

    const bool bigS = ws_size >= 272 * MiB;
    float* Sf       = bigS ? (float*)(base + 144 * MiB) : (float*)base;
    const int chunk = bigS ? 8 : 2;

    const dim3 blk(256);

    // ---- cast inputs / weights ----
    cast_bf16<<<dim3(MD / 1024), blk, 0, stream>>>(I,  bI,  MD);
    cast_bf16<<<dim3(MD / 1024), blk, 0, stream>>>(WQ, bWQ, MD);
    cast_bf16<<<dim3(MD / 1024), blk, 0, stream>>>(WK, bWK, MD);
    cast_bf16<<<dim3(MD / 1024), blk, 0, stream>>>(WV, bWV, MD);
    transpose_to_bf16<<<dim3(D / 32, D / 32), blk, 0, stream>>>(WZ,   bWZT,   D, D);
    transpose_to_bf16<<<dim3(C / 32, D / 32), blk, 0, stream>>>(WFFA, bWFFAT, D, C);
    transpose_to_bf16<<<dim3(D / 32, C / 32), blk, 0, stream>>>(WFFB, bWFFBT, C, D);

    // ---- QKV projections: [M,D] x [D,D]^T ; V written transposed ----
    gemm_bt<bf16_t, false><<<dim3(16, 16, 1), blk, 0, stream>>>(bI, bWQ, bQ,  M, D, D, D, D, D, 0, 0, 0);
    gemm_bt<bf16_t, false><<<dim3(16, 16, 1), blk, 0, stream>>>(bI, bWK, bK,  M, D, D, D, D, D, 0, 0, 0);
    gemm_bt<bf16_t, true ><<<dim3(16, 16, 1), blk, 0, stream>>>(bI, bWV, bVT, M, D, D, D, D, M, 0, 0, 0);

    // ---- attention, `chunk` heads per pass; S fp32, P bf16 in place ----
    for (int c0 = 0; c0 < 16; c0 += chunk) {
        // S[z][m][p] = Q[m, hE:] . K[p, hE:], K-extent 128
        gemm_bt<float, false><<<dim3(16, 16, chunk), blk, 0, stream>>>(
            bQ + c0 * E, bK + c0 * E, Sf,
            M, M, E, D, D, M, E, E, (long long)M * M);
        softmax_rows_bf16<<<dim3(M, chunk), blk, 0, stream>>>(Sf, M, (long long)M * M);
        // AV[m][hE+e] = P[m,:] . VT[hE+e,:]   (P bf16 in-place, lda = 2M)
        gemm_bt<bf16_t, false><<<dim3(1, 16, chunk), blk, 0, stream>>>(
            (const bf16_t*)Sf, bVT + (long long)c0 * E * M, bAV + c0 * E,
            M, E, M, 2 * M, M, D, 2LL * M * M, (long long)E * M, (long long)E);
    }

    // ---- Z = AV x WZ ----
    gemm_bt<bf16_t, false><<<dim3(16, 16, 1), blk, 0, stream>>>(bAV, bWZT, bZ, M, D, D, D, D, D, 0, 0, 0);
    // ---- FFA = Z x WFFA  ([M,2048] x [2048,8192]) ----
    gemm_bt<bf16_t, false><<<dim3(64, 16, 1), blk, 0, stream>>>(bZ, bWFFAT, bFFA, M, C, D, D, D, C, 0, 0, 0);
    // ---- FFB = FFA x WFFB ([M,8192] x [8192,2048]) -> fp32 out ----
    gemm_bt<float, false><<<dim3(16, 16, 1), blk, 0, stream>>>(bFFA, bWFFBT, out, M, D, C, C, C, D, 0, 0, 0);
}

// Round 5
// 687.723 us; speedup vs baseline: 7.2698x; 1.8464x over previous
//
#include <hip/hip_runtime.h>
#include <hip/hip_bf16.h>
#include <math.h>

// GPT3 block on MI355X, round 5 (= round 4 + `if constexpr` fix):
//  - flash attention (no S materialization): grid 32x16, online softmax,
//    QK+PV MFMA, XOR-swizzled LDS staging (global_load_lds forbids padding)
//  - QKV as one z=3 batched GEMM (V written transposed via ct_z epilogue)
//  - FFB split-K=4 with fp32 atomicAdd into zeroed d_out
// ws fixed 144 MiB: bI bWQ bWK bWV | bQ bK bVT bAV bZ bWZT | bWFFAT bWFFBT
// bFFA aliases [0,33.5MB) (bI..bWV + 1.5MB of bQ — all dead by then).

typedef __bf16 bf16_t;
typedef __bf16 bf16x8 __attribute__((ext_vector_type(8)));
typedef float  f32x4  __attribute__((ext_vector_type(4)));

#define AS1 __attribute__((address_space(1)))
#define AS3 __attribute__((address_space(3)))

__device__ __forceinline__ void load16_lds(const bf16_t* g, bf16_t* l) {
    // 16B per lane, LDS dest = wave-uniform base + lane*16
    __builtin_amdgcn_global_load_lds((AS1 void*)g, (AS3 void*)l, 16, 0, 0);
}

// ---------------- GEMM (m97 structure) ----------------
// C = A * B^T over storage: A [M,K] lda, B [N,K] ldb, C [M,N] ldc.
// Batched over blockIdx.z. If z == ct_z, write C^T (bf16) to ctc (ld=ldct).
// ATOMIC: atomicAdd into C (fp32 split-K reduction).
template<typename TOUT, bool ATOMIC>
__global__ __launch_bounds__(256)
void gemm_bt(const bf16_t* __restrict__ A, const bf16_t* __restrict__ B,
             TOUT* __restrict__ Cc, int Mdim, int Ndim, int Kdim,
             int lda, int ldb, int ldc,
             long long ab, long long bb, long long cb,
             int ct_z, bf16_t* __restrict__ ctc, int ldct)
{
    __shared__ bf16_t As[128 * 32];
    __shared__ bf16_t Bs[128 * 32];

    const int z = blockIdx.z;
    A  += (long long)z * ab;
    B  += (long long)z * bb;
    Cc += (long long)z * cb;

    const int bm = blockIdx.y * 128;
    const int bn = blockIdx.x * 128;
    const int t  = threadIdx.x;
    const int lane = t & 63;
    const int w    = t >> 6;

    const int wm = (w & 1) * 64;
    const int wn = (w >> 1) * 64;

    const int sub = lane >> 2;     // row within 16
    const int seg = lane & 3;      // 16B segment within 64B row

    const bf16_t* Ag0 = A + (long long)(bm + w * 32 + sub) * lda + seg * 8;
    const bf16_t* Ag1 = Ag0 + 16LL * lda;
    const bf16_t* Bg0 = B + (long long)(bn + w * 32 + sub) * ldb + seg * 8;
    const bf16_t* Bg1 = Bg0 + 16LL * ldb;

    bf16_t* Al0 = &As[(w * 2 + 0) * 512];
    bf16_t* Al1 = &As[(w * 2 + 1) * 512];
    bf16_t* Bl0 = &Bs[(w * 2 + 0) * 512];
    bf16_t* Bl1 = &Bs[(w * 2 + 1) * 512];

    const int col  = lane & 15;
    const int koff = (lane >> 4) * 8;

    f32x4 acc[4][4] = {};

    for (int k0 = 0; k0 < Kdim; k0 += 32) {
        load16_lds(Ag0 + k0, Al0);
        load16_lds(Ag1 + k0, Al1);
        load16_lds(Bg0 + k0, Bl0);
        load16_lds(Bg1 + k0, Bl1);
        __syncthreads();

        bf16x8 af[4], bfr[4];
        #pragma unroll
        for (int mi = 0; mi < 4; ++mi)
            af[mi] = *(const bf16x8*)&As[(wm + mi * 16 + col) * 32 + koff];
        #pragma unroll
        for (int nj = 0; nj < 4; ++nj)
            bfr[nj] = *(const bf16x8*)&Bs[(wn + nj * 16 + col) * 32 + koff];
        #pragma unroll
        for (int mi = 0; mi < 4; ++mi)
            #pragma unroll
            for (int nj = 0; nj < 4; ++nj)
                acc[mi][nj] = __builtin_amdgcn_mfma_f32_16x16x32_bf16(
                    af[mi], bfr[nj], acc[mi][nj], 0, 0, 0);
        __syncthreads();
    }

    // C/D layout: col = lane&15, row = (lane>>4)*4 + reg
    const int rbase = (lane >> 4) * 4;
    if (z == ct_z) {
        // write C^T[n][m] as bf16; 4 consecutive m -> one 8B store
        #pragma unroll
        for (int mi = 0; mi < 4; ++mi) {
            const long long mb = bm + wm + mi * 16 + rbase;
            #pragma unroll
            for (int nj = 0; nj < 4; ++nj) {
                const long long n = bn + wn + nj * 16 + col;
                union { bf16_t b[4]; unsigned long long u; } o;
                #pragma unroll
                for (int r = 0; r < 4; ++r) o.b[r] = (bf16_t)acc[mi][nj][r];
                *(unsigned long long*)(ctc + n * ldct + mb) = o.u;
            }
        }
    } else {
        #pragma unroll
        for (int mi = 0; mi < 4; ++mi) {
            #pragma unroll
            for (int r = 0; r < 4; ++r) {
                long long m = bm + wm + mi * 16 + rbase + r;
                TOUT* crow = Cc + m * ldc + bn + wn + col;
                #pragma unroll
                for (int nj = 0; nj < 4; ++nj) {
                    if constexpr (ATOMIC)
                        atomicAdd(&crow[nj * 16], (float)acc[mi][nj][r]);
                    else
                        crow[nj * 16] = (TOUT)acc[mi][nj][r];
                }
            }
        }
    }
}

// ---------------- flash attention ----------------
// Grid (M/64, H). Block 256 = 4 waves; wave owns 16 q-rows. KV tile = 64.
// Q [M,D], K [M,D], VT [D,M]; out AV [M,D] bf16. No 1/sqrt(E) scale.
__global__ __launch_bounds__(256, 2)
void flash_attn(const bf16_t* __restrict__ Q, const bf16_t* __restrict__ K,
                const bf16_t* __restrict__ VT, bf16_t* __restrict__ O,
                int M, int D)
{
    __shared__ bf16_t Kt[64 * 128];    // [p][e], col chunks XOR-swizzled by p&15
    __shared__ bf16_t Vt[128 * 64];    // [e][p], col chunks XOR-swizzled by e&7
    __shared__ bf16_t Pl[4 * 16 * 88]; // per-wave P [16][64], stride 88 (2-way)

    const int t = threadIdx.x, lane = t & 63, w = t >> 6;
    const int q4 = lane >> 4;          // quad 0..3
    const int c  = lane & 15;
    const int bm = blockIdx.x * 64;
    const int hE = blockIdx.y * 128;

    // loop-invariant Q A-frags: af_q[ks] = Q[bm + w*16 + c][hE + ks*32 + q4*8..]
    bf16x8 af_q[4];
    {
        const bf16_t* qrow = Q + (long long)(bm + w * 16 + c) * D + hE + q4 * 8;
        #pragma unroll
        for (int ks = 0; ks < 4; ++ks)
            af_q[ks] = *(const bf16x8*)(qrow + ks * 32);
    }

    f32x4 acc_o[8] = {};
    float m_i[4] = {-INFINITY, -INFINITY, -INFINITY, -INFINITY};
    float l_i[4] = {0.f, 0.f, 0.f, 0.f};

    bf16_t* Pw = &Pl[w * 16 * 88];

    for (int p0 = 0; p0 < M; p0 += 64) {
        // ---- stage K rows [p0..p0+64) and VT rows [hE..hE+128) ----
        #pragma unroll
        for (int j = 0; j < 4; ++j) {
            // K: 4 rows/call, 16B chunk c swizzled by row&15 = j*4+q4
            int krow = w * 16 + j * 4;
            load16_lds(K + (long long)(p0 + krow + q4) * D + hE + ((c ^ (j * 4 + q4)) * 8),
                       &Kt[krow * 128]);
            // VT: 8 rows/call, 8 chunks, swizzled by row&7 = lane>>3
            int vrow = w * 32 + j * 8;
            load16_lds(VT + (long long)(hE + vrow + (lane >> 3)) * M + p0
                          + (((lane & 7) ^ (lane >> 3)) * 8),
                       &Vt[vrow * 64]);
        }
        __syncthreads();

        // ---- S = Q K^T : wave computes [16, 64] ----
        f32x4 acc_s[4] = {};
        #pragma unroll
        for (int ks = 0; ks < 4; ++ks) {
            #pragma unroll
            for (int nj = 0; nj < 4; ++nj) {
                int row = nj * 16 + c;
                bf16x8 bk = *(const bf16x8*)&Kt[row * 128 + (((ks * 4 + q4) ^ c) * 8)];
                acc_s[nj] = __builtin_amdgcn_mfma_f32_16x16x32_bf16(
                    af_q[ks], bk, acc_s[nj], 0, 0, 0);
            }
        }

        // ---- online softmax (rows = q4*4 + r, cols across lane&15 and nj) ----
        float mt[4], alpha[4], rs[4];
        #pragma unroll
        for (int r = 0; r < 4; ++r) {
            float v = fmaxf(fmaxf(acc_s[0][r], acc_s[1][r]),
                            fmaxf(acc_s[2][r], acc_s[3][r]));
            #pragma unroll
            for (int off = 1; off < 16; off <<= 1)
                v = fmaxf(v, __shfl_xor(v, off));
            mt[r] = v;
        }
        #pragma unroll
        for (int r = 0; r < 4; ++r) {
            float mn = fmaxf(m_i[r], mt[r]);
            alpha[r] = __expf(m_i[r] - mn);
            m_i[r] = mn;
            rs[r] = 0.f;
        }
        #pragma unroll
        for (int nj = 0; nj < 4; ++nj)
            #pragma unroll
            for (int r = 0; r < 4; ++r) {
                float p = __expf(acc_s[nj][r] - m_i[r]);
                rs[r] += p;
                Pw[(q4 * 4 + r) * 88 + nj * 16 + c] = (bf16_t)p;
            }
        #pragma unroll
        for (int r = 0; r < 4; ++r) {
            float v = rs[r];
            #pragma unroll
            for (int off = 1; off < 16; off <<= 1)
                v += __shfl_xor(v, off);
            l_i[r] = alpha[r] * l_i[r] + v;
        }
        #pragma unroll
        for (int nj = 0; nj < 8; ++nj)
            #pragma unroll
            for (int r = 0; r < 4; ++r)
                acc_o[nj][r] *= alpha[r];
        __syncthreads();   // P visible to all lanes of the wave

        // ---- O += P V : A = P [m][p], B = Vt [e][p] ----
        #pragma unroll
        for (int ks = 0; ks < 2; ++ks) {
            bf16x8 ap = *(const bf16x8*)&Pw[c * 88 + ks * 32 + q4 * 8];
            #pragma unroll
            for (int nj = 0; nj < 8; ++nj) {
                int row = nj * 16 + c;
                bf16x8 bv = *(const bf16x8*)&Vt[row * 64 + (((ks * 4 + q4) ^ (c & 7)) * 8)];
                acc_o[nj] = __builtin_amdgcn_mfma_f32_16x16x32_bf16(
                    ap, bv, acc_o[nj], 0, 0, 0);
            }
        }
        __syncthreads();   // Kt/Vt reads done before next staging
    }

    // ---- epilogue: O / l ----
    float inv[4];
    #pragma unroll
    for (int r = 0; r < 4; ++r) inv[r] = 1.0f / l_i[r];
    #pragma unroll
    for (int nj = 0; nj < 8; ++nj)
        #pragma unroll
        for (int r = 0; r < 4; ++r)
            O[(long long)(bm + w * 16 + q4 * 4 + r) * D + hE + nj * 16 + c] =
                (bf16_t)(acc_o[nj][r] * inv[r]);
}

// ---------------- small utility kernels ----------------
// 4 casts fused: blockIdx.y selects src/dst pair (all length n)
__global__ __launch_bounds__(256)
void cast4_bf16(const float* __restrict__ s0, const float* __restrict__ s1,
                const float* __restrict__ s2, const float* __restrict__ s3,
                bf16_t* __restrict__ d0, long long seg, long long n)
{
    const float* src = (blockIdx.y == 0) ? s0 : (blockIdx.y == 1) ? s1
                     : (blockIdx.y == 2) ? s2 : s3;
    bf16_t* dst = d0 + (long long)blockIdx.y * seg;
    long long i = ((long long)blockIdx.x * 256 + threadIdx.x) * 4;
    if (i >= n) return;
    float4 v = *(const float4*)(src + i);
    union { bf16_t b[4]; unsigned long long u; } o;
    o.b[0] = (bf16_t)v.x; o.b[1] = (bf16_t)v.y;
    o.b[2] = (bf16_t)v.z; o.b[3] = (bf16_t)v.w;
    *(unsigned long long*)(dst + i) = o.u;
}

__global__ __launch_bounds__(256)
void transpose_to_bf16(const float* __restrict__ in, bf16_t* __restrict__ out,
                       int rows, int cols)
{
    __shared__ bf16_t tile[32][33];
    const int r0 = blockIdx.y * 32, c0 = blockIdx.x * 32;
    const int tx = threadIdx.x & 31, ty = threadIdx.x >> 5;
    #pragma unroll
    for (int i = 0; i < 4; ++i) {
        int r = ty + i * 8;
        tile[r][tx] = (bf16_t)in[(long long)(r0 + r) * cols + c0 + tx];
    }
    __syncthreads();
    #pragma unroll
    for (int i = 0; i < 4; ++i) {
        int r = ty + i * 8;
        out[(long long)(c0 + r) * rows + r0 + tx] = tile[tx][r];
    }
}

__global__ __launch_bounds__(256)
void zero_f32(float* __restrict__ p, long long n)
{
    long long i = ((long long)blockIdx.x * 256 + threadIdx.x) * 4;
    if (i >= n) return;
    *(float4*)(p + i) = float4{0.f, 0.f, 0.f, 0.f};
}

extern "C" void kernel_launch(void* const* d_in, const int* in_sizes, int n_in,
                              void* d_out, int out_size, void* d_ws, size_t ws_size,
                              hipStream_t stream)
{
    const float* I    = (const float*)d_in[0];
    const float* WV   = (const float*)d_in[1];
    const float* WK   = (const float*)d_in[2];
    const float* WQ   = (const float*)d_in[3];
    const float* WZ   = (const float*)d_in[4];
    const float* WFFA = (const float*)d_in[5];
    const float* WFFB = (const float*)d_in[6];
    float* out = (float*)d_out;                  // [M, D] fp32

    const int M = 2048, D = 2048, C = 8192;
    const long long MD = (long long)M * D;
    const size_t MiB = 1024 * 1024;

    char* base = (char*)d_ws;
    bf16_t* bI     = (bf16_t*)(base + 0 * MiB);
    bf16_t* bWQ    = (bf16_t*)(base + 8 * MiB);    // contiguous WQ,WK,WV (z-batch)
    bf16_t* bWK    = (bf16_t*)(base + 16 * MiB);
    bf16_t* bWV    = (bf16_t*)(base + 24 * MiB);
    bf16_t* bQ     = (bf16_t*)(base + 32 * MiB);   // contiguous Q,K (z-batch out)
    bf16_t* bK     = (bf16_t*)(base + 40 * MiB);
    bf16_t* bVT    = (bf16_t*)(base + 48 * MiB);   // [D, M] via ct_z epilogue
    bf16_t* bAV    = (bf16_t*)(base + 56 * MiB);
    bf16_t* bZ     = (bf16_t*)(base + 64 * MiB);
    bf16_t* bWZT   = (bf16_t*)(base + 72 * MiB);
    bf16_t* bWFFAT = (bf16_t*)(base + 80 * MiB);   // [C, D]
    bf16_t* bWFFBT = (bf16_t*)(base + 112 * MiB);  // [D, C]
    bf16_t* bFFA   = (bf16_t*)(base + 0 * MiB);    // [M, C] bf16 (bI..bQ-head dead)
    // total: 144 MiB

    const dim3 blk(256);

    // ---- prep: casts + weight transposes ----
    cast4_bf16<<<dim3(MD / 1024, 4), blk, 0, stream>>>(I, WQ, WK, WV, bI, MD, MD);
    transpose_to_bf16<<<dim3(D / 32, D / 32), blk, 0, stream>>>(WZ,   bWZT,   D, D);
    transpose_to_bf16<<<dim3(C / 32, D / 32), blk, 0, stream>>>(WFFA, bWFFAT, D, C);
    transpose_to_bf16<<<dim3(D / 32, C / 32), blk, 0, stream>>>(WFFB, bWFFBT, C, D);

    // ---- QKV in one z=3 dispatch (768 blocks); V -> bVT transposed ----
    gemm_bt<bf16_t, false><<<dim3(16, 16, 3), blk, 0, stream>>>(
        bI, bWQ, bQ, M, D, D, D, D, D, 0, MD, MD, /*ct_z=*/2, bVT, M);

    // ---- flash attention: Q,K,VT -> AV ----
    flash_attn<<<dim3(M / 64, 16), blk, 0, stream>>>(bQ, bK, bVT, bAV, M, D);

    // ---- Z = AV x WZ^T ----
    gemm_bt<bf16_t, false><<<dim3(16, 16, 1), blk, 0, stream>>>(
        bAV, bWZT, bZ, M, D, D, D, D, D, 0, 0, 0, -1, nullptr, 0);

    // ---- FFA = Z x WFFA^T  (1024 blocks) ----
    gemm_bt<bf16_t, false><<<dim3(64, 16, 1), blk, 0, stream>>>(
        bZ, bWFFAT, bFFA, M, C, D, D, D, C, 0, 0, 0, -1, nullptr, 0);

    // ---- FFB = FFA x WFFB^T, split-K=4 with atomic f32 accumulate ----
    zero_f32<<<dim3((int)(MD / 1024)), blk, 0, stream>>>(out, MD);
    gemm_bt<float, true><<<dim3(16, 16, 4), blk, 0, stream>>>(
        bFFA, bWFFBT, out, M, D, 2048, C, C, D, 2048, 2048, 0, -1, nullptr, 0);
}